// Round 3
// baseline (102.667 us; speedup 1.0000x reference)
//
#include <hip/hip_runtime.h>

// RBF: out[b,l] = exp(-(1/256) * max(||x_b||^2 + ||l_l||^2 - 2 x_b·l_l, 0))
// B=8192, L=2048, D=256.
// R3: single fused kernel. Stage fp32 -> bf16 in-register (v_cvt_pk_bf16_f32
// via native __bf16 fptrunc), ds_write_b128 into XOR-swizzled LDS, per-row
// squared norms accumulated during staging (each block sees full K for its
// rows). No workspace, no prepass, one dispatch.

typedef __bf16 bf16x8 __attribute__((ext_vector_type(8)));
typedef float  f32x4  __attribute__((ext_vector_type(4)));

#define B_ROWS 8192
#define L_ROWS 2048
#define K_DIM  256
#define NEG_GAMMA (-1.0f / 256.0f)

__global__ __launch_bounds__(256) void rbf_fused_kernel(
    const float* __restrict__ x,    // [8192][256]
    const float* __restrict__ lm,   // [2048][256]
    float* __restrict__ out)        // [8192][2048]
{
    // LDS: tiles are [128 rows][64 cols] bf16, physical 8-elem col-block =
    // logical ^ (row & 7) so ds_read_b128 fragment reads are conflict-free.
    __shared__ unsigned short As[128 * 64];  // landmarks tile, 16 KB
    __shared__ unsigned short Bs[128 * 64];  // x tile, 16 KB
    __shared__ float sqA[128][4];            // per-row partial sumsq, 2 KB
    __shared__ float sqB[128][4];            // 2 KB
    __shared__ float nA[128];                // -gamma*||l||^2
    __shared__ float nB[128];                // -gamma*||x||^2

    const int tid  = threadIdx.x;
    const int wave = tid >> 6;
    const int lane = tid & 63;
    const int wm = wave >> 1, wn = wave & 1;
    const int bn = blockIdx.x;   // x tile (64)
    const int bm = blockIdx.y;   // landmark tile (16)

    f32x4 acc[4][4];
    #pragma unroll
    for (int i = 0; i < 4; ++i)
        #pragma unroll
        for (int j = 0; j < 4; ++j)
            acc[i][j] = (f32x4){0.f, 0.f, 0.f, 0.f};

    // Staging assignment: 4 threads per row; thread t covers rows (t>>2) and
    // (t>>2)+64, contiguous 64B slice ss*16..ss*16+15 floats of the k-chunk.
    const int srow = tid >> 2;   // 0..63
    const int ss   = tid & 3;    // 16-float slice

    const float* Ag = lm + (size_t)(bm * 128) * K_DIM;
    const float* Bg = x  + (size_t)(bn * 128) * K_DIM;

    float aA0 = 0.f, aA1 = 0.f, aB0 = 0.f, aB1 = 0.f;

    const int rlo = lane & 15;   // row-within-16-tile for frag reads
    const int q   = lane >> 4;   // quad

    for (int k0 = 0; k0 < K_DIM; k0 += 64) {
        // stage one (row, 16-float slice) of one tile; convert + sumsq
        auto stage = [&](const float* __restrict__ gbase,
                         unsigned short* __restrict__ sbase,
                         int row, float& sacc) {
            const float* g = gbase + (size_t)row * K_DIM + k0 + ss * 16;
            f32x4 f0 = ((const f32x4*)g)[0];
            f32x4 f1 = ((const f32x4*)g)[1];
            f32x4 f2 = ((const f32x4*)g)[2];
            f32x4 f3 = ((const f32x4*)g)[3];
            #pragma unroll
            for (int i = 0; i < 4; ++i) {
                sacc = fmaf(f0[i], f0[i], sacc);
                sacc = fmaf(f1[i], f1[i], sacc);
                sacc = fmaf(f2[i], f2[i], sacc);
                sacc = fmaf(f3[i], f3[i], sacc);
            }
            bf16x8 h0 = __builtin_convertvector(
                __builtin_shufflevector(f0, f1, 0,1,2,3,4,5,6,7), bf16x8);
            bf16x8 h1 = __builtin_convertvector(
                __builtin_shufflevector(f2, f3, 0,1,2,3,4,5,6,7), bf16x8);
            const int c = row & 7;
            *(bf16x8*)&sbase[row * 64 + (((2*ss)     ^ c) * 8)] = h0;
            *(bf16x8*)&sbase[row * 64 + (((2*ss + 1) ^ c) * 8)] = h1;
        };
        stage(Ag, As, srow,      aA0);
        stage(Ag, As, srow + 64, aA1);
        stage(Bg, Bs, srow,      aB0);
        stage(Bg, Bs, srow + 64, aB1);
        __syncthreads();

        #pragma unroll
        for (int kk = 0; kk < 64; kk += 32) {
            const int kb = (kk >> 3) + q;            // logical k-block 0..7
            const int pb = (kb ^ (rlo & 7)) * 8;     // physical col offset
            bf16x8 af[4], bfr[4];
            #pragma unroll
            for (int t = 0; t < 4; ++t) {
                af[t]  = *(const bf16x8*)&As[(wm*64 + t*16 + rlo) * 64 + pb];
                bfr[t] = *(const bf16x8*)&Bs[(wn*64 + t*16 + rlo) * 64 + pb];
            }
            #pragma unroll
            for (int mt = 0; mt < 4; ++mt)
                #pragma unroll
                for (int nt = 0; nt < 4; ++nt)
                    acc[mt][nt] = __builtin_amdgcn_mfma_f32_16x16x32_bf16(
                        af[mt], bfr[nt], acc[mt][nt], 0, 0, 0);
        }
        __syncthreads();
    }

    // Per-row norms: each thread saw cols {ss*16..ss*16+15} of every k-chunk
    // for its two rows of each tile -> 4 partials per row, reduce in LDS.
    sqA[srow][ss]      = aA0;
    sqA[srow + 64][ss] = aA1;
    sqB[srow][ss]      = aB0;
    sqB[srow + 64][ss] = aB1;
    __syncthreads();
    if (tid < 128) {
        nA[tid] = NEG_GAMMA * (sqA[tid][0] + sqA[tid][1] + sqA[tid][2] + sqA[tid][3]);
    } else {
        const int r = tid - 128;
        nB[r] = NEG_GAMMA * (sqB[r][0] + sqB[r][1] + sqB[r][2] + sqB[r][3]);
    }
    __syncthreads();

    // Epilogue. C/D: col(lane&15)=b within tile, row(quad*4+reg)=l within tile.
    const float twog = 2.0f / 256.0f;
    const int bt0 = wn * 64 + rlo;        // b within tile
    const int lt0 = wm * 64 + q * 4;      // l within tile (reg base)
    #pragma unroll
    for (int nt = 0; nt < 4; ++nt) {
        const int bt = bt0 + nt * 16;
        const float gx = nB[bt];
        float* orow = out + (size_t)(bn * 128 + bt) * L_ROWS + bm * 128;
        #pragma unroll
        for (int mt = 0; mt < 4; ++mt) {
            const int lt = lt0 + mt * 16;
            const f32x4 gl = *(const f32x4*)&nA[lt];
            f32x4 o;
            #pragma unroll
            for (int r = 0; r < 4; ++r)
                o[r] = __expf(fminf(fmaf(twog, acc[mt][nt][r], gx + gl[r]), 0.f));
            __builtin_nontemporal_store(o, (f32x4*)&orow[lt]);
        }
    }
}

extern "C" void kernel_launch(void* const* d_in, const int* in_sizes, int n_in,
                              void* d_out, int out_size, void* d_ws, size_t ws_size,
                              hipStream_t stream) {
    const float* x  = (const float*)d_in[0];   // [8192, 256]
    const float* lm = (const float*)d_in[1];   // [2048, 256]
    float* out = (float*)d_out;
    rbf_fused_kernel<<<dim3(B_ROWS/128, L_ROWS/128), 256, 0, stream>>>(x, lm, out);
}

// Round 4
// 98.217 us; speedup vs baseline: 1.0453x; 1.0453x over previous
//
#include <hip/hip_runtime.h>

// RBF: out[b,l] = exp(-(1/256) * max(||x_b||^2 + ||l_l||^2 - 2 x_b·l_l, 0))
// B=8192, L=2048, D=256.
// R4: revert R3 fusion (fp32 staging + VALU ds_write cost ~5us). Back to R2:
//     bf16 prepass -> ws, then global_load_lds GEMM (XOR-swizzled LDS,
//     conflict-free ds_read_b128), fused exp epilogue, float4 NT stores.
//     GEMM is write-BW-bound (64 MB @ ~6 TB/s ~= 11 us); total sits at
//     harness floor (~85 us poison/restore) + ~12-14 us kernel time.

typedef __bf16 bf16x8 __attribute__((ext_vector_type(8)));
typedef float  f32x4  __attribute__((ext_vector_type(4)));

#define B_ROWS 8192
#define L_ROWS 2048
#define K_DIM  256
#define NEG_GAMMA (-1.0f / 256.0f)

#define GLD_LDS(g, l) __builtin_amdgcn_global_load_lds(                      \
    (const __attribute__((address_space(1))) void*)(g),                      \
    (__attribute__((address_space(3))) void*)(l), 16, 0, 0)

__device__ __forceinline__ unsigned short f32_to_bf16_rne(float f) {
    union { float f; unsigned int u; } v; v.f = f;
    unsigned int u = v.u;
    return (unsigned short)((u + 0x7fffu + ((u >> 16) & 1u)) >> 16);
}

// One wave per 256-float row (x rows then landmark rows): bf16 convert (RNE)
// + store -gamma * ||row||^2.
__global__ __launch_bounds__(256) void cvt_rows_kernel(
    const float* __restrict__ x, const float* __restrict__ lm,
    unsigned short* __restrict__ xb, unsigned short* __restrict__ lb,
    float* __restrict__ gx2, float* __restrict__ gl2)
{
    const int lane = threadIdx.x & 63;
    const int row  = blockIdx.x * 4 + (threadIdx.x >> 6);
    const float* src; unsigned short* dst; float* nrm;
    if (row < B_ROWS) {
        src = x + (size_t)row * K_DIM; dst = xb + (size_t)row * K_DIM; nrm = gx2 + row;
    } else {
        const int r = row - B_ROWS;
        src = lm + (size_t)r * K_DIM; dst = lb + (size_t)r * K_DIM; nrm = gl2 + r;
    }
    const float4 v = ((const float4*)src)[lane];
    ushort4 o;
    o.x = f32_to_bf16_rne(v.x);
    o.y = f32_to_bf16_rne(v.y);
    o.z = f32_to_bf16_rne(v.z);
    o.w = f32_to_bf16_rne(v.w);
    ((ushort4*)dst)[lane] = o;
    float s = v.x*v.x + v.y*v.y + v.z*v.z + v.w*v.w;
    #pragma unroll
    for (int off = 32; off > 0; off >>= 1) s += __shfl_down(s, off, 64);
    if (lane == 0) nrm[0] = NEG_GAMMA * s;
}

// 128x128 tile, NT, 4 waves 2x2, each wave 64x64 via 4x4 of 16x16x32 bf16 MFMA.
// M = landmarks (2048), N = x (8192) -> C/D lane mapping gives each lane 4
// consecutive l's at fixed b => float4 stores into out[b][l].
// LDS: [128 rows][64 cols] bf16, physical col-block = logical ^ (row & 7).
__global__ __launch_bounds__(256) void rbf_gemm_kernel(
    const unsigned short* __restrict__ Lmat,  // landmarks bf16 [2048][256]
    const unsigned short* __restrict__ Xmat,  // x bf16 [8192][256]
    const float* __restrict__ gl2,            // -gamma*||l||^2 [2048]
    const float* __restrict__ gx2,            // -gamma*||x||^2 [8192]
    float* __restrict__ out)                  // [8192][2048]
{
    __shared__ unsigned short As[128 * 64];  // landmarks tile, 16 KB
    __shared__ unsigned short Bs[128 * 64];  // x tile, 16 KB

    const int tid  = threadIdx.x;
    const int wave = tid >> 6;
    const int lane = tid & 63;
    const int wm = wave >> 1, wn = wave & 1;
    const int bn = blockIdx.x;   // x tile (64)
    const int bm = blockIdx.y;   // landmark tile (16)

    f32x4 acc[4][4];
    #pragma unroll
    for (int i = 0; i < 4; ++i)
        #pragma unroll
        for (int j = 0; j < 4; ++j)
            acc[i][j] = (f32x4){0.f, 0.f, 0.f, 0.f};

    // Staging (global_load_lds: wave-uniform base + lane*16B):
    // lane l -> LDS row base+(l>>3), physical col-block (l&7).
    // Fetch logical col-block (l&7)^(l>>3) so logical block c of row rr sits
    // at physical block c ^ (rr & 7)  -> conflict-free ds_read_b128 frags.
    const int lrow = lane >> 3;             // 0..7
    const int lblk = (lane & 7) ^ lrow;     // logical k-block fetched

    const unsigned short* Ab = Lmat + (size_t)(bm * 128) * K_DIM;
    const unsigned short* Bb = Xmat + (size_t)(bn * 128) * K_DIM;

    const int rlo = lane & 15;   // row-within-16-tile for frag reads
    const int q   = lane >> 4;   // quad

    for (int k0 = 0; k0 < K_DIM; k0 += 64) {
        #pragma unroll
        for (int it = 0; it < 4; ++it) {
            const int r = wave * 32 + it * 8;
            GLD_LDS(Ab + (size_t)(r + lrow) * K_DIM + k0 + lblk * 8, &As[r * 64]);
            GLD_LDS(Bb + (size_t)(r + lrow) * K_DIM + k0 + lblk * 8, &Bs[r * 64]);
        }
        __syncthreads();

        #pragma unroll
        for (int kk = 0; kk < 64; kk += 32) {
            const int kb = (kk >> 3) + q;            // logical k-block
            const int pb = (kb ^ (rlo & 7)) * 8;     // physical col offset
            bf16x8 af[4], bfr[4];
            #pragma unroll
            for (int t = 0; t < 4; ++t) {
                af[t]  = *(const bf16x8*)&As[(wm*64 + t*16 + rlo) * 64 + pb];
                bfr[t] = *(const bf16x8*)&Bs[(wn*64 + t*16 + rlo) * 64 + pb];
            }
            #pragma unroll
            for (int mt = 0; mt < 4; ++mt)
                #pragma unroll
                for (int nt = 0; nt < 4; ++nt)
                    acc[mt][nt] = __builtin_amdgcn_mfma_f32_16x16x32_bf16(
                        af[mt], bfr[nt], acc[mt][nt], 0, 0, 0);
        }
        __syncthreads();
    }

    // Epilogue. C/D: col(lane&15)=b within tile, row(quad*4+reg)=l within tile.
    const float twog = 2.0f / 256.0f;
    const int b0 = bn * 128 + wn * 64 + rlo;
    const int l0 = bm * 128 + wm * 64 + q * 4;
    #pragma unroll
    for (int nt = 0; nt < 4; ++nt) {
        const int b = b0 + nt * 16;
        const float gx = gx2[b];
        float* orow = out + (size_t)b * L_ROWS;
        #pragma unroll
        for (int mt = 0; mt < 4; ++mt) {
            const int l = l0 + mt * 16;
            const float4 gl = *(const float4*)&gl2[l];
            f32x4 o;
            o[0] = __expf(fminf(fmaf(twog, acc[mt][nt][0], gx + gl.x), 0.f));
            o[1] = __expf(fminf(fmaf(twog, acc[mt][nt][1], gx + gl.y), 0.f));
            o[2] = __expf(fminf(fmaf(twog, acc[mt][nt][2], gx + gl.z), 0.f));
            o[3] = __expf(fminf(fmaf(twog, acc[mt][nt][3], gx + gl.w), 0.f));
            __builtin_nontemporal_store(o, (f32x4*)&orow[l]);
        }
    }
}

extern "C" void kernel_launch(void* const* d_in, const int* in_sizes, int n_in,
                              void* d_out, int out_size, void* d_ws, size_t ws_size,
                              hipStream_t stream) {
    const float* x  = (const float*)d_in[0];   // [8192, 256]
    const float* lm = (const float*)d_in[1];   // [2048, 256]
    float* out = (float*)d_out;

    char* ws = (char*)d_ws;
    unsigned short* xb = (unsigned short*)ws;                               // 4 MB
    unsigned short* lb = (unsigned short*)(ws + (size_t)B_ROWS*K_DIM*2);    // 1 MB
    float* gx2 = (float*)(ws + (size_t)B_ROWS*K_DIM*2 + (size_t)L_ROWS*K_DIM*2);
    float* gl2 = gx2 + B_ROWS;

    cvt_rows_kernel<<<(B_ROWS + L_ROWS)/4, 256, 0, stream>>>(x, lm, xb, lb, gx2, gl2);
    rbf_gemm_kernel<<<dim3(B_ROWS/128, L_ROWS/128), 256, 0, stream>>>(lb, xb, gl2, gx2, out);
}